// Round 10
// baseline (373.384 us; speedup 1.0000x reference)
//
#include <hip/hip_runtime.h>

#define N_NODES 100000
#define N_EDGES 800000
#define NEG 0.2f
#define PB_SHIFT 8
#define PB_NODES 256
#define N_PBKT ((N_NODES + PB_NODES - 1) / PB_NODES)   // 391
#define CAP 4096        // fixed slab capacity per bucket (mean 2048, 16-sigma headroom)
#define TILE_E 4096
#define EPT 16          // edges per thread in partition (TILE_E / 256)
#define PART_BLOCKS ((N_EDGES + TILE_E - 1) / TILE_E)  // 196
#define GEMM_BLOCKS ((N_NODES + 127) / 128)            // 782
#define SMEM_INTS (CAP + 4 * PB_NODES)                 // 5120 ints = 20 KB

typedef __attribute__((ext_vector_type(8))) short bf16x8;
typedef __attribute__((ext_vector_type(4))) float f32x4;

__device__ inline unsigned short f2bf(float f) {   // RNE f32 -> bf16
    unsigned u = __float_as_uint(f);
    u += 0x7fffu + ((u >> 16) & 1u);
    return (unsigned short)(u >> 16);
}
__device__ inline float bf2f_lo(unsigned u) { return __uint_as_float(u << 16); }
__device__ inline float bf2f_hi(unsigned u) { return __uint_as_float(u & 0xffff0000u); }

// ---------------------------------------------------------------------------
// prep_w: pack W (and Aalpha = W·a, ct==8) into MFMA B-fragment order.
// Also zeroes slab cursors + flag, adj pads, and seeds offs[N].
// ---------------------------------------------------------------------------
__global__ __launch_bounds__(256) void prep_w_kernel(
    const float* __restrict__ W_in, const float* __restrict__ W_out,
    const float* __restrict__ as_in, const float* __restrict__ ad_in,
    const float* __restrict__ as_out, const float* __restrict__ ad_out,
    unsigned short* __restrict__ Wf, int* __restrict__ gcur,
    int* __restrict__ adj_in, int* __restrict__ adj_out,
    int* __restrict__ offs_in, int* __restrict__ offs_out)
{
    const int t = blockIdx.x * 256 + threadIdx.x;
    if (t < 2 * N_PBKT + 1) gcur[t] = 0;      // +1: the part_done flag
    if (t < 8) { adj_in[N_EDGES + t] = 0; adj_out[N_EDGES + t] = 0; }
    if (t == 0) { offs_in[N_NODES] = N_EDGES; offs_out[N_NODES] = N_EDGES; }
    if (t >= 2 * 4 * 9 * 64) return;
    const int lane = t & 63;
    const int rest = t >> 6;
    const int ct  = rest % 9;
    const int kb  = (rest / 9) & 3;
    const int dir = rest / 36;
    const float* W  = dir ? W_out  : W_in;
    const float* as = dir ? as_out : as_in;
    const float* ad = dir ? ad_out : ad_in;
    const int m16 = lane & 15, quad = lane >> 4;

    bf16x8 o;
#pragma unroll
    for (int j = 0; j < 8; ++j) {
        const int k = kb * 32 + quad * 8 + j;
        float v;
        if (ct < 8) {
            v = W[k * 128 + ct * 16 + m16];
        } else {
            const float* av = (m16 < 8) ? as : ad;
            const int hh = m16 & 7;
            v = 0.f;
            for (int c = 0; c < 16; ++c)
                v += W[k * 128 + hh * 16 + c] * av[hh * 16 + c];
        }
        o[j] = (short)f2bf(v);
    }
    *(bf16x8*)&Wf[(long long)t * 8] = o;
}

// ---------------------------------------------------------------------------
// mega kernel: role-split grid.
//   blocks [0, PART_BLOCKS): partition their edge tile, fence+flag, spin until
//     all PART_BLOCKS flagged (deadlock-proof: every spinner has already
//     flagged, and 196 blocks always fit co-resident), then run place for 4
//     bucket-dirs each — place overlaps the gemm bulk instead of being a
//     separate serial dispatch.
//   blocks [PART_BLOCKS, PART_BLOCKS+2*GEMM_BLOCKS): split-dir MFMA gemm.
// ---------------------------------------------------------------------------
__global__ __launch_bounds__(256) void mega_kernel(
    const float* __restrict__ x,
    const unsigned short* __restrict__ Wf,
    unsigned short* __restrict__ h_in, unsigned short* __restrict__ h_out,
    float* __restrict__ asrc_in, float* __restrict__ adst_in,
    float* __restrict__ asrc_out, float* __restrict__ adst_out,
    const int* __restrict__ ei, int* __restrict__ gcur,
    int* __restrict__ binned0, int* __restrict__ binned1,
    int* __restrict__ adj_in, int* __restrict__ adj_out,
    int* __restrict__ offs_in, int* __restrict__ offs_out)
{
    __shared__ int smem[SMEM_INTS];
    const int tid = threadIdx.x;

    if (blockIdx.x < PART_BLOCKS) {
        // ---------------- partition role ----------------
        int* hist0 = smem;
        int* curs0 = smem + N_PBKT;
        int* hist1 = smem + 2 * N_PBKT;
        int* curs1 = smem + 3 * N_PBKT;
        for (int i = tid; i < N_PBKT; i += 256) { hist0[i] = 0; hist1[i] = 0; }
        __syncthreads();

        const int e0 = blockIdx.x * TILE_E;
        int sv[EPT], tv[EPT];
#pragma unroll
        for (int i = 0; i < EPT; ++i) {
            const int e = e0 + i * 256 + tid;
            if (e < N_EDGES) {
                sv[i] = ei[e];
                tv[i] = ei[N_EDGES + e];
                atomicAdd(&hist0[tv[i] >> PB_SHIFT], 1);   // dir0: by dst
                atomicAdd(&hist1[sv[i] >> PB_SHIFT], 1);   // dir1: by src
            } else {
                sv[i] = -1; tv[i] = 0;
            }
        }
        __syncthreads();
        for (int b = tid; b < N_PBKT; b += 256) {
            int c = hist0[b];
            curs0[b] = c ? atomicAdd(&gcur[b], c) : 0;
            c = hist1[b];
            curs1[b] = c ? atomicAdd(&gcur[N_PBKT + b], c) : 0;
        }
        __syncthreads();
#pragma unroll
        for (int i = 0; i < EPT; ++i) {
            if (sv[i] >= 0) {
                const int b0 = tv[i] >> PB_SHIFT;
                int pos = atomicAdd(&curs0[b0], 1);
                if (pos < CAP)
                    binned0[b0 * CAP + pos] = (sv[i] << 8) | (tv[i] & (PB_NODES - 1));
                const int b1 = sv[i] >> PB_SHIFT;
                pos = atomicAdd(&curs1[b1], 1);
                if (pos < CAP)
                    binned1[b1 * CAP + pos] = (tv[i] << 8) | (sv[i] & (PB_NODES - 1));
            }
        }

        // ---- release: make this block's slab writes device-visible, flag ----
        int* flag = gcur + 2 * N_PBKT;
        __threadfence();            // every thread drains+flushes its stores
        __syncthreads();
        if (tid == 0)
            __hip_atomic_fetch_add(flag, 1, __ATOMIC_RELEASE, __HIP_MEMORY_SCOPE_AGENT);
        // ---- acquire: wait for all partition blocks ----
        if (tid == 0) {
            while (__hip_atomic_load(flag, __ATOMIC_ACQUIRE, __HIP_MEMORY_SCOPE_AGENT) < PART_BLOCKS)
                __builtin_amdgcn_s_sleep(2);
        }
        __syncthreads();
        __threadfence();            // invalidate stale cached lines

        // ---------------- place role (4 bucket-dirs per block) ----------------
        int* slab = smem;
        int* cnt  = smem + CAP;
        int* sc   = cnt + PB_NODES;
        int* cur  = sc + PB_NODES;
        int* red  = cur + PB_NODES;

        for (int u = 0; u < 4; ++u) {
            const int bd = u * PART_BLOCKS + blockIdx.x;
            if (bd >= 2 * N_PBKT) break;
            const int dir = bd >= N_PBKT;
            const int b   = bd - dir * N_PBKT;
            const int* bp = (dir ? binned1 : binned0) + b * CAP;
            const int* gc = gcur + dir * N_PBKT;
            int* adj  = dir ? adj_out  : adj_in;
            int* offs = dir ? offs_out : offs_in;
            const int base = b << PB_SHIFT;
            const int cntb = min(gc[b], CAP);

            __syncthreads();   // protect smem reuse across iterations/roles
            // bucket base: sum of min(gc[j],CAP) for j < b
            int part = 0;
            for (int j = tid; j < b; j += 256) part += min(gc[j], CAP);
            red[tid] = part;
            cnt[tid] = 0;
            for (int p = tid; p < cntb; p += 256) slab[p] = bp[p];
            __syncthreads();
#pragma unroll
            for (int off = 128; off > 0; off >>= 1) {
                if (tid < off) red[tid] += red[tid + off];
                __syncthreads();
            }
            const int beg = red[0];
            for (int p = tid; p < cntb; p += 256)
                atomicAdd(&cnt[slab[p] & (PB_NODES - 1)], 1);
            __syncthreads();
            const int v = cnt[tid];
            sc[tid] = v;
            __syncthreads();
#pragma unroll
            for (int off = 1; off < PB_NODES; off <<= 1) {
                int t2 = (tid >= off) ? sc[tid - off] : 0;
                __syncthreads();
                sc[tid] += t2;
                __syncthreads();
            }
            const int excl = beg + sc[tid] - v;
            cur[tid] = excl;
            const int node = base + tid;
            if (node < N_NODES) offs[node] = excl;
            __syncthreads();
            for (int p = tid; p < cntb; p += 256) {
                const int pk = slab[p];
                adj[atomicAdd(&cur[pk & (PB_NODES - 1)], 1)] = pk >> 8;
            }
        }
        return;
    }

    // ---------------- gemm role (split dirs, round-7 form) ----------------
    const int gb  = blockIdx.x - PART_BLOCKS;
    const int dir = gb >= GEMM_BLOCKS;
    const int bx  = gb - dir * GEMM_BLOCKS;
    unsigned short* h = dir ? h_out : h_in;
    float* asrc = dir ? asrc_out : asrc_in;
    float* adst = dir ? adst_out : adst_in;

    const int lane = tid & 63;
    const int wave = tid >> 6;
    const int m16  = lane & 15;
    const int quad = lane >> 4;
    const int rbase = bx * 128 + wave * 32;

    f32x4 acc[2][8];
    f32x4 acc_a[2];
#pragma unroll
    for (int rt = 0; rt < 2; ++rt) {
        acc_a[rt] = f32x4{0.f, 0.f, 0.f, 0.f};
#pragma unroll
        for (int ct = 0; ct < 8; ++ct)
            acc[rt][ct] = f32x4{0.f, 0.f, 0.f, 0.f};
    }

    const unsigned short* wf = Wf + (long long)dir * 4 * 9 * 64 * 8;

#pragma unroll
    for (int kb = 0; kb < 4; ++kb) {
        const int k0 = kb * 32 + quad * 8;
        bf16x8 a[2];
#pragma unroll
        for (int rt = 0; rt < 2; ++rt) {
            int r = rbase + rt * 16 + m16;
            r = r < N_NODES ? r : N_NODES - 1;   // clamp: stores are guarded
            const float4 v0 = *(const float4*)&x[(long long)r * 128 + k0];
            const float4 v1 = *(const float4*)&x[(long long)r * 128 + k0 + 4];
            a[rt][0] = (short)f2bf(v0.x); a[rt][1] = (short)f2bf(v0.y);
            a[rt][2] = (short)f2bf(v0.z); a[rt][3] = (short)f2bf(v0.w);
            a[rt][4] = (short)f2bf(v1.x); a[rt][5] = (short)f2bf(v1.y);
            a[rt][6] = (short)f2bf(v1.z); a[rt][7] = (short)f2bf(v1.w);
        }
#pragma unroll
        for (int ct = 0; ct < 9; ++ct) {
            const bf16x8 b = *(const bf16x8*)&wf[(long long)((kb * 9 + ct) * 64 + lane) * 8];
            if (ct < 8) {
                acc[0][ct] = __builtin_amdgcn_mfma_f32_16x16x32_bf16(a[0], b, acc[0][ct], 0, 0, 0);
                acc[1][ct] = __builtin_amdgcn_mfma_f32_16x16x32_bf16(a[1], b, acc[1][ct], 0, 0, 0);
            } else {
                acc_a[0] = __builtin_amdgcn_mfma_f32_16x16x32_bf16(a[0], b, acc_a[0], 0, 0, 0);
                acc_a[1] = __builtin_amdgcn_mfma_f32_16x16x32_bf16(a[1], b, acc_a[1], 0, 0, 0);
            }
        }
    }

#pragma unroll
    for (int rt = 0; rt < 2; ++rt) {
#pragma unroll
        for (int r = 0; r < 4; ++r) {
            const int row = rbase + rt * 16 + quad * 4 + r;
            if (row < N_NODES) {
                unsigned short* hp = &h[(long long)row * 128 + m16];
#pragma unroll
                for (int ct = 0; ct < 8; ++ct)
                    hp[ct * 16] = f2bf(acc[rt][ct][r]);
                const float av = acc_a[rt][r];
                if (m16 < 8) asrc[row * 8 + m16] = av;
                else         adst[row * 8 + (m16 - 8)] = av;
            }
        }
    }
}

// ---------------------------------------------------------------------------
// Gather v5 (best measured): one wave per node, wave-uniform n so offs/adj go
// through the scalar pipe; single padded branch-free 8-stride loop; inline
// asrc+leaky+exp; shfl w-broadcast; den via 3x shfl_xor.
// ---------------------------------------------------------------------------
__global__ __launch_bounds__(256) void gather_kernel(
    const int* __restrict__ offs_in, const int* __restrict__ adj_in,
    const int* __restrict__ offs_out, const int* __restrict__ adj_out,
    const unsigned short* __restrict__ h_in, const unsigned short* __restrict__ h_out,
    const float* __restrict__ asrc_in, const float* __restrict__ adst_in,
    const float* __restrict__ asrc_out, const float* __restrict__ adst_out,
    const float* __restrict__ b_in, const float* __restrict__ b_out,
    float* __restrict__ out)
{
    int n = (blockIdx.x * 256 + threadIdx.x) >> 6;
    if (n >= N_NODES) return;
    n = __builtin_amdgcn_readfirstlane(n);
    const int lane = threadIdx.x & 63;
    const int c0 = lane * 2;
    const int hh = lane >> 3;        // head this lane accumulates for
    const int g8 = lane & 7;         // neighbor slot this lane owns
    const int grpbase = lane & 56;   // hh*8: base lane of this head group

    float acc0 = b_in[c0] + b_out[c0];
    float acc1 = b_in[c0 + 1] + b_out[c0 + 1];

#define DIR_BLOCK(OFFS, ADJ, HX, ASRC, ADST)                                   \
    {                                                                          \
        const int beg = OFFS[n], end = OFFS[n + 1];                            \
        if (end > beg) {                                                       \
            const float ad = ADST[n * 8 + hh];                                 \
            float num0 = 0.f, num1 = 0.f, den = 0.f;                           \
            for (int p = beg; p < end; p += 8) {                               \
                const int q = p + g8;                                          \
                const int nbv = ADJ[q];               /* vector ld, padded */  \
                float l = ASRC[nbv * 8 + hh] + ad;                             \
                l = l > 0.f ? l : NEG * l;                                     \
                float w = __expf(l);                                           \
                w = (q < end) ? w : 0.f;                                       \
                den += w;                                                      \
                _Pragma("unroll")                                              \
                for (int g = 0; g < 8; ++g) {                                  \
                    const int nb = ADJ[p + g];        /* scalar (uniform) */   \
                    const float w_g = __shfl(w, grpbase + g, 64);              \
                    const unsigned hv = *(const unsigned*)&HX[(long long)nb * 128 + c0]; \
                    num0 += w_g * bf2f_lo(hv);                                 \
                    num1 += w_g * bf2f_hi(hv);                                 \
                }                                                              \
            }                                                                  \
            den += __shfl_xor(den, 1, 64);                                     \
            den += __shfl_xor(den, 2, 64);                                     \
            den += __shfl_xor(den, 4, 64);                                     \
            const float rden = 1.f / den;                                      \
            acc0 += num0 * rden;                                               \
            acc1 += num1 * rden;                                               \
        }                                                                      \
    }

    DIR_BLOCK(offs_in, adj_in, h_in, asrc_in, adst_in)
    DIR_BLOCK(offs_out, adj_out, h_out, asrc_out, adst_out)
#undef DIR_BLOCK

    *(float2*)&out[(long long)n * 128 + c0] = float2{acc0, acc1};
}

extern "C" void kernel_launch(void* const* d_in, const int* in_sizes, int n_in,
                              void* d_out, int out_size, void* d_ws, size_t ws_size,
                              hipStream_t stream) {
    const float* x      = (const float*)d_in[0];
    const int*   ei     = (const int*)  d_in[1];
    const float* W_in   = (const float*)d_in[2];
    const float* as_in  = (const float*)d_in[3];
    const float* ad_in  = (const float*)d_in[4];
    const float* b_in   = (const float*)d_in[5];
    const float* W_out  = (const float*)d_in[6];
    const float* as_out = (const float*)d_in[7];
    const float* ad_out = (const float*)d_in[8];
    const float* b_out  = (const float*)d_in[9];
    float* out = (float*)d_out;

    char* ws = (char*)d_ws;
    const long long NH = (long long)N_NODES * 128;
    unsigned short* h_in  = (unsigned short*)ws;    ws += NH * 2;
    unsigned short* h_out = (unsigned short*)ws;    ws += NH * 2;
    unsigned short* Wf    = (unsigned short*)ws;    ws += 2LL * 4 * 9 * 64 * 8 * 2;
    float* asrc_in   = (float*)ws;                  ws += N_NODES * 8 * 4;
    float* adst_in   = (float*)ws;                  ws += N_NODES * 8 * 4;
    float* asrc_out  = (float*)ws;                  ws += N_NODES * 8 * 4;
    float* adst_out  = (float*)ws;                  ws += N_NODES * 8 * 4;
    int* binned0     = (int*)ws;                    ws += (long long)N_PBKT * CAP * 4;
    int* binned1     = (int*)ws;                    ws += (long long)N_PBKT * CAP * 4;
    int* adj_in      = (int*)ws;                    ws += (N_EDGES + 8) * 4;
    int* adj_out     = (int*)ws;                    ws += (N_EDGES + 8) * 4;
    int* offs_in     = (int*)ws;                    ws += (N_NODES + 1) * 4;
    int* offs_out    = (int*)ws;                    ws += (N_NODES + 1) * 4;
    int* gcur        = (int*)ws;                    ws += (2 * N_PBKT + 1) * 4;  // +flag

    prep_w_kernel<<<(2 * 4 * 9 * 64 + 255) / 256, 256, 0, stream>>>(
        W_in, W_out, as_in, ad_in, as_out, ad_out, Wf, gcur,
        adj_in, adj_out, offs_in, offs_out);

    mega_kernel<<<PART_BLOCKS + 2 * GEMM_BLOCKS, 256, 0, stream>>>(
        x, Wf, h_in, h_out, asrc_in, adst_in, asrc_out, adst_out,
        ei, gcur, binned0, binned1, adj_in, adj_out, offs_in, offs_out);

    gather_kernel<<<(N_NODES * 64 + 255) / 256, 256, 0, stream>>>(
        offs_in, adj_in, offs_out, adj_out, h_in, h_out,
        asrc_in, adst_in, asrc_out, adst_out, b_in, b_out, out);
}

// Round 11
// 255.662 us; speedup vs baseline: 1.4605x; 1.4605x over previous
//
#include <hip/hip_runtime.h>

#define N_NODES 100000
#define N_EDGES 800000
#define NEG 0.2f
#define PB_SHIFT 8
#define PB_NODES 256
#define N_PBKT ((N_NODES + PB_NODES - 1) / PB_NODES)   // 391
#define CAP 4096        // fixed slab capacity per bucket (mean 2048, 16-sigma headroom)
#define TILE_E 4096
#define EPT 16          // edges per thread in partition (TILE_E / 256)
#define PART_BLOCKS ((N_EDGES + TILE_E - 1) / TILE_E)  // 196
#define GEMM_BLOCKS ((N_NODES + 127) / 128)            // 782

typedef __attribute__((ext_vector_type(8))) short bf16x8;
typedef __attribute__((ext_vector_type(4))) float f32x4;

__device__ inline unsigned short f2bf(float f) {   // RNE f32 -> bf16
    unsigned u = __float_as_uint(f);
    u += 0x7fffu + ((u >> 16) & 1u);
    return (unsigned short)(u >> 16);
}
__device__ inline float bf2f_lo(unsigned u) { return __uint_as_float(u << 16); }
__device__ inline float bf2f_hi(unsigned u) { return __uint_as_float(u & 0xffff0000u); }

// ---------------------------------------------------------------------------
// prep_w: pack W (and Aalpha = W·a, ct==8) into MFMA B-fragment order.
// Also zeroes the slab cursors, adj pads, and seeds offs[N].
// ---------------------------------------------------------------------------
__global__ __launch_bounds__(256) void prep_w_kernel(
    const float* __restrict__ W_in, const float* __restrict__ W_out,
    const float* __restrict__ as_in, const float* __restrict__ ad_in,
    const float* __restrict__ as_out, const float* __restrict__ ad_out,
    unsigned short* __restrict__ Wf, int* __restrict__ gcur,
    int* __restrict__ adj_in, int* __restrict__ adj_out,
    int* __restrict__ offs_in, int* __restrict__ offs_out)
{
    const int t = blockIdx.x * 256 + threadIdx.x;
    if (t < 2 * N_PBKT) gcur[t] = 0;
    if (t < 8) { adj_in[N_EDGES + t] = 0; adj_out[N_EDGES + t] = 0; }
    if (t == 0) { offs_in[N_NODES] = N_EDGES; offs_out[N_NODES] = N_EDGES; }
    if (t >= 2 * 4 * 9 * 64) return;
    const int lane = t & 63;
    const int rest = t >> 6;
    const int ct  = rest % 9;
    const int kb  = (rest / 9) & 3;
    const int dir = rest / 36;
    const float* W  = dir ? W_out  : W_in;
    const float* as = dir ? as_out : as_in;
    const float* ad = dir ? ad_out : ad_in;
    const int m16 = lane & 15, quad = lane >> 4;

    bf16x8 o;
#pragma unroll
    for (int j = 0; j < 8; ++j) {
        const int k = kb * 32 + quad * 8 + j;
        float v;
        if (ct < 8) {
            v = W[k * 128 + ct * 16 + m16];
        } else {
            const float* av = (m16 < 8) ? as : ad;
            const int hh = m16 & 7;
            v = 0.f;
            for (int c = 0; c < 16; ++c)
                v += W[k * 128 + hh * 16 + c] * av[hh * 16 + c];
        }
        o[j] = (short)f2bf(v);
    }
    *(bf16x8*)&Wf[(long long)t * 8] = o;
}

// ---------------------------------------------------------------------------
// mega kernel: role-split grid. Blocks [0, PART_BLOCKS) run the edge
// partition (latency/LDS-bound, placed FIRST so they start early); blocks
// [PART_BLOCKS, PART_BLOCKS + 2*GEMM_BLOCKS) run the split-dir MFMA gemm
// (BW-bound). Disjoint inputs/outputs; the partition work hides under the
// gemm stream. NOTE (round-10 lesson): static LDS is allocated per-KERNEL,
// so the partition role's 6.2 KB is the kernel-wide footprint — keeping it
// small preserves the gemm role's occupancy. Do NOT grow it to 20 KB.
// ---------------------------------------------------------------------------
__global__ __launch_bounds__(256) void mega_kernel(
    const float* __restrict__ x,
    const unsigned short* __restrict__ Wf,
    unsigned short* __restrict__ h_in, unsigned short* __restrict__ h_out,
    float* __restrict__ asrc_in, float* __restrict__ adst_in,
    float* __restrict__ asrc_out, float* __restrict__ adst_out,
    const int* __restrict__ ei, int* __restrict__ gcur,
    int* __restrict__ binned0, int* __restrict__ binned1)
{
    const int tid = threadIdx.x;

    if (blockIdx.x < PART_BLOCKS) {
        // ---------------- partition role ----------------
        __shared__ int hist0[N_PBKT];
        __shared__ int curs0[N_PBKT];
        __shared__ int hist1[N_PBKT];
        __shared__ int curs1[N_PBKT];
        for (int i = tid; i < N_PBKT; i += 256) { hist0[i] = 0; hist1[i] = 0; }
        __syncthreads();

        const int e0 = blockIdx.x * TILE_E;
        int sv[EPT], tv[EPT];
#pragma unroll
        for (int i = 0; i < EPT; ++i) {
            const int e = e0 + i * 256 + tid;
            if (e < N_EDGES) {
                sv[i] = ei[e];
                tv[i] = ei[N_EDGES + e];
                atomicAdd(&hist0[tv[i] >> PB_SHIFT], 1);   // dir0: by dst
                atomicAdd(&hist1[sv[i] >> PB_SHIFT], 1);   // dir1: by src
            } else {
                sv[i] = -1; tv[i] = 0;
            }
        }
        __syncthreads();
        for (int b = tid; b < N_PBKT; b += 256) {
            int c = hist0[b];
            curs0[b] = c ? atomicAdd(&gcur[b], c) : 0;
            c = hist1[b];
            curs1[b] = c ? atomicAdd(&gcur[N_PBKT + b], c) : 0;
        }
        __syncthreads();
#pragma unroll
        for (int i = 0; i < EPT; ++i) {
            if (sv[i] >= 0) {
                const int b0 = tv[i] >> PB_SHIFT;
                int pos = atomicAdd(&curs0[b0], 1);
                if (pos < CAP)
                    binned0[b0 * CAP + pos] = (sv[i] << 8) | (tv[i] & (PB_NODES - 1));
                const int b1 = sv[i] >> PB_SHIFT;
                pos = atomicAdd(&curs1[b1], 1);
                if (pos < CAP)
                    binned1[b1 * CAP + pos] = (tv[i] << 8) | (sv[i] & (PB_NODES - 1));
            }
        }
        return;
    }

    // ---------------- gemm role (split dirs, round-7 form) ----------------
    const int gb  = blockIdx.x - PART_BLOCKS;
    const int dir = gb >= GEMM_BLOCKS;
    const int bx  = gb - dir * GEMM_BLOCKS;
    unsigned short* h = dir ? h_out : h_in;
    float* asrc = dir ? asrc_out : asrc_in;
    float* adst = dir ? adst_out : adst_in;

    const int lane = tid & 63;
    const int wave = tid >> 6;
    const int m16  = lane & 15;
    const int quad = lane >> 4;
    const int rbase = bx * 128 + wave * 32;

    f32x4 acc[2][8];
    f32x4 acc_a[2];
#pragma unroll
    for (int rt = 0; rt < 2; ++rt) {
        acc_a[rt] = f32x4{0.f, 0.f, 0.f, 0.f};
#pragma unroll
        for (int ct = 0; ct < 8; ++ct)
            acc[rt][ct] = f32x4{0.f, 0.f, 0.f, 0.f};
    }

    const unsigned short* wf = Wf + (long long)dir * 4 * 9 * 64 * 8;

#pragma unroll
    for (int kb = 0; kb < 4; ++kb) {
        const int k0 = kb * 32 + quad * 8;
        bf16x8 a[2];
#pragma unroll
        for (int rt = 0; rt < 2; ++rt) {
            int r = rbase + rt * 16 + m16;
            r = r < N_NODES ? r : N_NODES - 1;   // clamp: stores are guarded
            const float4 v0 = *(const float4*)&x[(long long)r * 128 + k0];
            const float4 v1 = *(const float4*)&x[(long long)r * 128 + k0 + 4];
            a[rt][0] = (short)f2bf(v0.x); a[rt][1] = (short)f2bf(v0.y);
            a[rt][2] = (short)f2bf(v0.z); a[rt][3] = (short)f2bf(v0.w);
            a[rt][4] = (short)f2bf(v1.x); a[rt][5] = (short)f2bf(v1.y);
            a[rt][6] = (short)f2bf(v1.z); a[rt][7] = (short)f2bf(v1.w);
        }
#pragma unroll
        for (int ct = 0; ct < 9; ++ct) {
            const bf16x8 b = *(const bf16x8*)&wf[(long long)((kb * 9 + ct) * 64 + lane) * 8];
            if (ct < 8) {
                acc[0][ct] = __builtin_amdgcn_mfma_f32_16x16x32_bf16(a[0], b, acc[0][ct], 0, 0, 0);
                acc[1][ct] = __builtin_amdgcn_mfma_f32_16x16x32_bf16(a[1], b, acc[1][ct], 0, 0, 0);
            } else {
                acc_a[0] = __builtin_amdgcn_mfma_f32_16x16x32_bf16(a[0], b, acc_a[0], 0, 0, 0);
                acc_a[1] = __builtin_amdgcn_mfma_f32_16x16x32_bf16(a[1], b, acc_a[1], 0, 0, 0);
            }
        }
    }

#pragma unroll
    for (int rt = 0; rt < 2; ++rt) {
#pragma unroll
        for (int r = 0; r < 4; ++r) {
            const int row = rbase + rt * 16 + quad * 4 + r;
            if (row < N_NODES) {
                unsigned short* hp = &h[(long long)row * 128 + m16];
#pragma unroll
                for (int ct = 0; ct < 8; ++ct)
                    hp[ct * 16] = f2bf(acc[rt][ct][r]);
                const float av = acc_a[rt][r];
                if (m16 < 8) asrc[row * 8 + m16] = av;
                else         adst[row * 8 + (m16 - 8)] = av;
            }
        }
    }
}

// ---------------------------------------------------------------------------
// place v3: one block per bucket. Computes its own bucket base (masked sum of
// min(gcur[j],CAP), j<b — L2-hot, replaces the scan dispatch), stages the
// slab in LDS ONCE (kills the second global pass), then fine count+scan+
// scatter entirely from LDS. adj writes land in a contiguous ~8KB region.
// ---------------------------------------------------------------------------
__global__ __launch_bounds__(256) void place_kernel(
    const int* __restrict__ binned0, const int* __restrict__ binned1,
    const int* __restrict__ gcur,
    int* __restrict__ adj_in, int* __restrict__ adj_out,
    int* __restrict__ offs_in, int* __restrict__ offs_out)
{
    const int b   = blockIdx.x;
    const int dir = blockIdx.y;
    const int* bp = (dir ? binned1 : binned0) + b * CAP;
    const int* gc = gcur + dir * N_PBKT;
    int* adj  = dir ? adj_out  : adj_in;
    int* offs = dir ? offs_out : offs_in;

    const int base = b << PB_SHIFT;
    const int tid = threadIdx.x;
    const int cntb = min(gc[b], CAP);

    __shared__ int slab[CAP];
    __shared__ int cnt[PB_NODES];
    __shared__ int sc[PB_NODES];
    __shared__ int cur[PB_NODES];
    __shared__ int red[PB_NODES];

    // bucket base: sum of min(gc[j],CAP) for j < b
    int part = 0;
    for (int j = tid; j < b; j += 256) part += min(gc[j], CAP);
    red[tid] = part;
    cnt[tid] = 0;
    // stage slab into LDS
    for (int p = tid; p < cntb; p += 256) slab[p] = bp[p];
    __syncthreads();
#pragma unroll
    for (int off = 128; off > 0; off >>= 1) {
        if (tid < off) red[tid] += red[tid + off];
        __syncthreads();
    }
    const int beg = red[0];
    // fine count
    for (int p = tid; p < cntb; p += 256)
        atomicAdd(&cnt[slab[p] & (PB_NODES - 1)], 1);
    __syncthreads();
    const int v = cnt[tid];
    sc[tid] = v;
    __syncthreads();
#pragma unroll
    for (int off = 1; off < PB_NODES; off <<= 1) {
        int t = (tid >= off) ? sc[tid - off] : 0;
        __syncthreads();
        sc[tid] += t;
        __syncthreads();
    }
    const int excl = beg + sc[tid] - v;
    cur[tid] = excl;
    const int node = base + tid;
    if (node < N_NODES) offs[node] = excl;
    __syncthreads();
    for (int p = tid; p < cntb; p += 256) {
        const int pk = slab[p];
        adj[atomicAdd(&cur[pk & (PB_NODES - 1)], 1)] = pk >> 8;
    }
}

// ---------------------------------------------------------------------------
// Gather v5 (best measured): one wave per node, wave-uniform n so offs/adj go
// through the scalar pipe; single padded branch-free 8-stride loop; inline
// asrc+leaky+exp; shfl w-broadcast; den via 3x shfl_xor.
// ---------------------------------------------------------------------------
__global__ __launch_bounds__(256) void gather_kernel(
    const int* __restrict__ offs_in, const int* __restrict__ adj_in,
    const int* __restrict__ offs_out, const int* __restrict__ adj_out,
    const unsigned short* __restrict__ h_in, const unsigned short* __restrict__ h_out,
    const float* __restrict__ asrc_in, const float* __restrict__ adst_in,
    const float* __restrict__ asrc_out, const float* __restrict__ adst_out,
    const float* __restrict__ b_in, const float* __restrict__ b_out,
    float* __restrict__ out)
{
    int n = (blockIdx.x * 256 + threadIdx.x) >> 6;
    if (n >= N_NODES) return;
    n = __builtin_amdgcn_readfirstlane(n);
    const int lane = threadIdx.x & 63;
    const int c0 = lane * 2;
    const int hh = lane >> 3;        // head this lane accumulates for
    const int g8 = lane & 7;         // neighbor slot this lane owns
    const int grpbase = lane & 56;   // hh*8: base lane of this head group

    float acc0 = b_in[c0] + b_out[c0];
    float acc1 = b_in[c0 + 1] + b_out[c0 + 1];

#define DIR_BLOCK(OFFS, ADJ, HX, ASRC, ADST)                                   \
    {                                                                          \
        const int beg = OFFS[n], end = OFFS[n + 1];                            \
        if (end > beg) {                                                       \
            const float ad = ADST[n * 8 + hh];                                 \
            float num0 = 0.f, num1 = 0.f, den = 0.f;                           \
            for (int p = beg; p < end; p += 8) {                               \
                const int q = p + g8;                                          \
                const int nbv = ADJ[q];               /* vector ld, padded */  \
                float l = ASRC[nbv * 8 + hh] + ad;                             \
                l = l > 0.f ? l : NEG * l;                                     \
                float w = __expf(l);                                           \
                w = (q < end) ? w : 0.f;                                       \
                den += w;                                                      \
                _Pragma("unroll")                                              \
                for (int g = 0; g < 8; ++g) {                                  \
                    const int nb = ADJ[p + g];        /* scalar (uniform) */   \
                    const float w_g = __shfl(w, grpbase + g, 64);              \
                    const unsigned hv = *(const unsigned*)&HX[(long long)nb * 128 + c0]; \
                    num0 += w_g * bf2f_lo(hv);                                 \
                    num1 += w_g * bf2f_hi(hv);                                 \
                }                                                              \
            }                                                                  \
            den += __shfl_xor(den, 1, 64);                                     \
            den += __shfl_xor(den, 2, 64);                                     \
            den += __shfl_xor(den, 4, 64);                                     \
            const float rden = 1.f / den;                                      \
            acc0 += num0 * rden;                                               \
            acc1 += num1 * rden;                                               \
        }                                                                      \
    }

    DIR_BLOCK(offs_in, adj_in, h_in, asrc_in, adst_in)
    DIR_BLOCK(offs_out, adj_out, h_out, asrc_out, adst_out)
#undef DIR_BLOCK

    *(float2*)&out[(long long)n * 128 + c0] = float2{acc0, acc1};
}

extern "C" void kernel_launch(void* const* d_in, const int* in_sizes, int n_in,
                              void* d_out, int out_size, void* d_ws, size_t ws_size,
                              hipStream_t stream) {
    const float* x      = (const float*)d_in[0];
    const int*   ei     = (const int*)  d_in[1];
    const float* W_in   = (const float*)d_in[2];
    const float* as_in  = (const float*)d_in[3];
    const float* ad_in  = (const float*)d_in[4];
    const float* b_in   = (const float*)d_in[5];
    const float* W_out  = (const float*)d_in[6];
    const float* as_out = (const float*)d_in[7];
    const float* ad_out = (const float*)d_in[8];
    const float* b_out  = (const float*)d_in[9];
    float* out = (float*)d_out;

    char* ws = (char*)d_ws;
    const long long NH = (long long)N_NODES * 128;
    unsigned short* h_in  = (unsigned short*)ws;    ws += NH * 2;
    unsigned short* h_out = (unsigned short*)ws;    ws += NH * 2;
    unsigned short* Wf    = (unsigned short*)ws;    ws += 2LL * 4 * 9 * 64 * 8 * 2;
    float* asrc_in   = (float*)ws;                  ws += N_NODES * 8 * 4;
    float* adst_in   = (float*)ws;                  ws += N_NODES * 8 * 4;
    float* asrc_out  = (float*)ws;                  ws += N_NODES * 8 * 4;
    float* adst_out  = (float*)ws;                  ws += N_NODES * 8 * 4;
    int* binned0     = (int*)ws;                    ws += (long long)N_PBKT * CAP * 4;
    int* binned1     = (int*)ws;                    ws += (long long)N_PBKT * CAP * 4;
    int* adj_in      = (int*)ws;                    ws += (N_EDGES + 8) * 4;
    int* adj_out     = (int*)ws;                    ws += (N_EDGES + 8) * 4;
    int* offs_in     = (int*)ws;                    ws += (N_NODES + 1) * 4;
    int* offs_out    = (int*)ws;                    ws += (N_NODES + 1) * 4;
    int* gcur        = (int*)ws;                    ws += 2 * N_PBKT * 4;

    prep_w_kernel<<<(2 * 4 * 9 * 64 + 255) / 256, 256, 0, stream>>>(
        W_in, W_out, as_in, ad_in, as_out, ad_out, Wf, gcur,
        adj_in, adj_out, offs_in, offs_out);

    mega_kernel<<<PART_BLOCKS + 2 * GEMM_BLOCKS, 256, 0, stream>>>(
        x, Wf, h_in, h_out, asrc_in, adst_in, asrc_out, adst_out,
        ei, gcur, binned0, binned1);

    place_kernel<<<dim3(N_PBKT, 2), 256, 0, stream>>>(
        binned0, binned1, gcur, adj_in, adj_out, offs_in, offs_out);

    gather_kernel<<<(N_NODES * 64 + 255) / 256, 256, 0, stream>>>(
        offs_in, adj_in, offs_out, adj_out, h_in, h_out,
        asrc_in, adst_in, asrc_out, adst_out, b_in, b_out, out);
}